// Round 3
// baseline (359.702 us; speedup 1.0000x reference)
//
#include <hip/hip_runtime.h>
#include <math.h>

// Lane layout: l = 16*g + q, g = group (0..3), q = quarter (0..15).
// Each per-b length-64 vector lives as float4/lane (d = 4q..4q+3), replicated
// across the 4 groups; group g's loads fetch row-slots c=g and c=g+4, so one
// vector-load instruction gathers 4 distinct rows (1 KB payload).
// TWO batch elements per wave: all index loads, then all row gathers for both
// b's issue before any compute consumes them (2x memory-level parallelism).
// agg_w loads are shared across the two b's. No LDS, no barriers.

__device__ __forceinline__ float4 ld4(const float* p) {
    return *reinterpret_cast<const float4*>(p);
}
__device__ __forceinline__ float dot4(float4 a, float4 b) {
    return fmaf(a.x, b.x, fmaf(a.y, b.y, fmaf(a.z, b.z, a.w * b.w)));
}
__device__ __forceinline__ float4 fma4(float s, float4 a, float4 acc) {
    acc.x = fmaf(s, a.x, acc.x);
    acc.y = fmaf(s, a.y, acc.y);
    acc.z = fmaf(s, a.z, acc.z);
    acc.w = fmaf(s, a.w, acc.w);
    return acc;
}
__device__ __forceinline__ float4 mul4(float4 a, float4 b) {
    return make_float4(a.x * b.x, a.y * b.y, a.z * b.z, a.w * b.w);
}
__device__ __forceinline__ float4 xgroup_sum4(float4 v) {  // sum over 4 groups
    v.x += __shfl_xor(v.x, 16, 64); v.x += __shfl_xor(v.x, 32, 64);
    v.y += __shfl_xor(v.y, 16, 64); v.y += __shfl_xor(v.y, 32, 64);
    v.z += __shfl_xor(v.z, 16, 64); v.z += __shfl_xor(v.z, 32, 64);
    v.w += __shfl_xor(v.w, 16, 64); v.w += __shfl_xor(v.w, 32, 64);
    return v;
}
__device__ __forceinline__ float4 shfl4(float4 v, int src) {
    float4 r;
    r.x = __shfl(v.x, src, 64);
    r.y = __shfl(v.y, src, 64);
    r.z = __shfl(v.z, src, 64);
    r.w = __shfl(v.w, src, 64);
    return r;
}

__global__ __launch_bounds__(256) void pifsa_gnn_kernel(
    const int*   __restrict__ u,          // [B]
    const int*   __restrict__ v,          // [B]
    const int*   __restrict__ uai,        // [B,8]
    const int*   __restrict__ adj_ent,    // [NUM_ENT,8]
    const int*   __restrict__ adj_rel,    // [NUM_ENT,8]
    const float* __restrict__ usr_emb,    // [NUM_USER,64]
    const float* __restrict__ ent_emb,    // [NUM_ENT,64]
    const float* __restrict__ rel_emb,    // [32,64]
    const float* __restrict__ conv_w,     // [1,8,3,3] OIHW
    const float* __restrict__ conv_b,     // [1]
    const float* __restrict__ agg_w,      // [64,64] (d,j) row-major
    const float* __restrict__ agg_b,      // [64]
    float*       __restrict__ out,        // [B]
    int B)
{
    const int widx = (blockIdx.x * 256 + threadIdx.x) >> 6;   // wave index
    const int b0   = widx * 2;
    if (b0 >= B) return;
    const bool two = (b0 + 1 < B);

    const int l  = threadIdx.x & 63;
    const int g  = l >> 4;
    const int q  = l & 15;
    const int d0 = q << 2;
    const int c0 = g, c1 = g + 4;

    int bb[2];
    bb[0] = b0;
    bb[1] = two ? b0 + 1 : b0;

    // ---------- phase 0: index loads for both b ----------
    int ub[2], vb[2];
#pragma unroll
    for (int t = 0; t < 2; ++t) { ub[t] = u[bb[t]]; vb[t] = v[bb[t]]; }

    int e0[2], e1[2], r0[2], r1[2], n0[2], n1[2];
#pragma unroll
    for (int t = 0; t < 2; ++t) {
        e0[t] = uai[bb[t] * 8 + c0];
        e1[t] = uai[bb[t] * 8 + c1];
        r0[t] = adj_rel[vb[t] * 8 + c0];
        r1[t] = adj_rel[vb[t] * 8 + c1];
        n0[t] = adj_ent[vb[t] * 8 + c0];
        n1[t] = adj_ent[vb[t] * 8 + c1];
    }

    // ---------- phase 1: all row gathers for both b ----------
    float4 usr[2], self4[2], a0[2], a1[2], nb0[2], nb1[2], re0[2], re1[2];
#pragma unroll
    for (int t = 0; t < 2; ++t) {
        usr[t]   = ld4(usr_emb + (size_t)ub[t] * 64 + d0);
        self4[t] = ld4(ent_emb + (size_t)vb[t] * 64 + d0);
        a0[t]    = ld4(ent_emb + (size_t)e0[t] * 64 + d0);
        a1[t]    = ld4(ent_emb + (size_t)e1[t] * 64 + d0);
        nb0[t]   = ld4(ent_emb + (size_t)n0[t] * 64 + d0);
        nb1[t]   = ld4(ent_emb + (size_t)n1[t] * 64 + d0);
        re0[t]   = ld4(rel_emb + (size_t)r0[t] * 64 + d0);
        re1[t]   = ld4(rel_emb + (size_t)r1[t] * 64 + d0);
    }

    // shared small params
    const float w0a = conv_w[c0 * 9 + 1], w1a = conv_w[c0 * 9 + 4], w2a = conv_w[c0 * 9 + 7];
    const float w0b = conv_w[c1 * 9 + 1], w1b = conv_w[c1 * 9 + 4], w2b = conv_w[c1 * 9 + 7];
    const float cb  = conv_b[0];
    const float4 bias = ld4(agg_b + d0);

    // ---------- phase 2: compute both b ----------
    float4 user_e[2], h4[2];
#pragma unroll
    for (int t = 0; t < 2; ++t) {
        // user side
        float4 ue0 = mul4(usr[t], a0[t]);
        float4 ue1 = mul4(usr[t], a1[t]);

        float4 cacc = make_float4(0.f, 0.f, 0.f, 0.f);
        {
            float pw = __shfl(ue0.w, (l - 1) & 63, 64); if (q == 0)  pw = 0.f;
            float nx = __shfl(ue0.x, (l + 1) & 63, 64); if (q == 15) nx = 0.f;
            cacc = fma4(w1a, ue0, cacc);
            cacc = fma4(w0a, make_float4(pw, ue0.x, ue0.y, ue0.z), cacc);
            cacc = fma4(w2a, make_float4(ue0.y, ue0.z, ue0.w, nx), cacc);
        }
        {
            float pw = __shfl(ue1.w, (l - 1) & 63, 64); if (q == 0)  pw = 0.f;
            float nx = __shfl(ue1.x, (l + 1) & 63, 64); if (q == 15) nx = 0.f;
            cacc = fma4(w1b, ue1, cacc);
            cacc = fma4(w0b, make_float4(pw, ue1.x, ue1.y, ue1.z), cacc);
            cacc = fma4(w2b, make_float4(ue1.y, ue1.z, ue1.w, nx), cacc);
        }
        cacc = xgroup_sum4(cacc);
        user_e[t] = make_float4(cacc.x + cb, cacc.y + cb, cacc.z + cb, cacc.w + cb);

        // attention scores over K=8
        float p0 = dot4(user_e[t], re0[t]);
        float p1 = dot4(user_e[t], re1[t]);
#pragma unroll
        for (int off = 1; off <= 8; off <<= 1) {
            p0 += __shfl_xor(p0, off, 64);
            p1 += __shfl_xor(p1, off, 64);
        }
        float s[8];
#pragma unroll
        for (int kk = 0; kk < 4; ++kk) {
            s[kk]     = __shfl(p0, kk * 16, 64);
            s[kk + 4] = __shfl(p1, kk * 16, 64);
        }
        float m = s[0];
#pragma unroll
        for (int k = 1; k < 8; ++k) m = fmaxf(m, s[k]);
        float den = 0.f, ek[8];
#pragma unroll
        for (int k = 0; k < 8; ++k) { ek[k] = __expf(s[k] - m); den += ek[k]; }
        const float inv_den = 1.f / den;

        // h = self + sum_k attn[k]*neigh[k]
        float4 hp = make_float4(0.f, 0.f, 0.f, 0.f);
        hp = fma4(ek[c0] * inv_den, nb0[t], hp);
        hp = fma4(ek[c1] * inv_den, nb1[t], hp);
        hp = xgroup_sum4(hp);
        h4[t] = make_float4(self4[t].x + hp.x, self4[t].y + hp.y,
                            self4[t].z + hp.z, self4[t].w + hp.w);
    }

    // ---------- phase 3: item matmul, agg_w shared across both b ----------
    float4 acc[2];
    acc[0] = make_float4(0.f, 0.f, 0.f, 0.f);
    acc[1] = make_float4(0.f, 0.f, 0.f, 0.f);
#pragma unroll
    for (int i = 0; i < 4; ++i) {
        const float* wrow = agg_w + (16 * g + 4 * i) * 64 + d0;
        const float4 w0 = ld4(wrow);
        const float4 w1 = ld4(wrow + 64);
        const float4 w2 = ld4(wrow + 128);
        const float4 w3 = ld4(wrow + 192);
#pragma unroll
        for (int t = 0; t < 2; ++t) {
            const float4 hb = shfl4(h4[t], 20 * g + i);   // h[16g+4i .. +3]
            acc[t] = fma4(hb.x, w0, acc[t]);
            acc[t] = fma4(hb.y, w1, acc[t]);
            acc[t] = fma4(hb.z, w2, acc[t]);
            acc[t] = fma4(hb.w, w3, acc[t]);
        }
    }

#pragma unroll
    for (int t = 0; t < 2; ++t) {
        float4 ac = xgroup_sum4(acc[t]);
        float4 item;
        item.x = 1.f / (1.f + __expf(-(ac.x + bias.x)));
        item.y = 1.f / (1.f + __expf(-(ac.y + bias.y)));
        item.z = 1.f / (1.f + __expf(-(ac.z + bias.z)));
        item.w = 1.f / (1.f + __expf(-(ac.w + bias.w)));

        float p = dot4(user_e[t], item);
#pragma unroll
        for (int off = 1; off <= 8; off <<= 1)
            p += __shfl_xor(p, off, 64);

        if (l == 0 && (t == 0 || two))
            out[bb[t]] = 1.f / (1.f + __expf(-p));
    }
}

extern "C" void kernel_launch(void* const* d_in, const int* in_sizes, int n_in,
                              void* d_out, int out_size, void* d_ws, size_t ws_size,
                              hipStream_t stream) {
    const int*   u        = (const int*)  d_in[0];
    const int*   v        = (const int*)  d_in[1];
    const int*   uai      = (const int*)  d_in[2];
    const int*   adj_ent  = (const int*)  d_in[3];
    const int*   adj_rel  = (const int*)  d_in[4];
    const float* usr_emb  = (const float*)d_in[5];
    const float* ent_emb  = (const float*)d_in[6];
    const float* rel_emb  = (const float*)d_in[7];
    const float* conv_w   = (const float*)d_in[8];
    const float* conv_b   = (const float*)d_in[9];
    const float* agg_w    = (const float*)d_in[10];
    const float* agg_b    = (const float*)d_in[11];
    float*       out      = (float*)d_out;

    const int B = in_sizes[0];
    const int nwaves = (B + 1) / 2;               // 2 batch elems per wave
    const int grid   = (nwaves + 3) / 4;          // 4 waves per 256-thread block
    pifsa_gnn_kernel<<<grid, 256, 0, stream>>>(
        u, v, uai, adj_ent, adj_rel, usr_emb, ent_emb, rel_emb,
        conv_w, conv_b, agg_w, agg_b, out, B);
}